// Round 2
// baseline (5280.643 us; speedup 1.0000x reference)
//
#include <hip/hip_runtime.h>
#include <stdint.h>

typedef float f32x4 __attribute__((ext_vector_type(4)));
typedef short s16x8 __attribute__((ext_vector_type(8)));

#define TLEN 4096
#define HID  128
#define NG   4   // 4 batch-groups of 16 (B = 64)
#define KSCALE 2.8853900817779268f   // 2*log2(e), folded into W_x, W_h, bias

static __device__ __forceinline__ float asf(uint32_t u) {
    union { uint32_t u; float f; } v; v.u = u; return v.f;
}
static __device__ __forceinline__ uint32_t cvtpk(float lo, float hi) {
    uint32_t r;
    asm("v_cvt_pk_bf16_f32 %0, %1, %2" : "=v"(r) : "v"(lo), "v"(hi));
    return r;
}
static __device__ __forceinline__ void splitbf(float v, unsigned short& hi, unsigned short& lo) {
    uint32_t p = cvtpk(v, 0.f);
    hi = (unsigned short)(p & 0xFFFFu);
    float r = v - asf((uint32_t)hi << 16);
    uint32_t q = cvtpk(r, 0.f);
    lo = (unsigned short)(q & 0xFFFFu);
}

// Row permutation: logical tile row r of (wave wv, tile d) -> global hidden
//   G = 32*wv + 4*d + 8*(r>>2) + (r&3)
// With this permutation, the MFMA C-layout (col=lane&15, row=(lane>>4)*4+j)
// packed via cvt_pk IS the next step's B-fragment layout for chunk kk=wv:
//   B chunk kk, vgpr q holds rows 32kk+8lg+{2q,2q+1}  (lo=even, hi=odd).

// ---------------- Phase 1: pre = (X @ W_x + bias) * 2log2e, permuted layout
__global__ __launch_bounds__(512) void pre_gemm(
        const float* __restrict__ X, const float* __restrict__ W,
        const float* __restrict__ bias, float* preB, int wsOK) {
    const int tid = threadIdx.x;
    const int w  = tid >> 6;      // 0..7 -> (wv = w>>1, d = w&1)
    const int l  = tid & 63;
    const int lg = l >> 4;
    const int lc = l & 15;
    const int g  = blockIdx.x & (NG - 1);
    const int t0 = (blockIdx.x >> 2) << 4;   // 16 timesteps per WG

    const int wv = w >> 1, dd = w & 1;
    const int GA = 32*wv + 4*dd + 8*(lc>>2) + (lc&3);  // A-row (lane lc) global col
    const int Gc = 32*wv + 4*dd + 8*lg;                // C-row base (this lane)

    // A = W_x^T (scaled) split hi/lo: A[r=lc][k], k = 32kk+8lg+j
    s16x8 ahi[4], alo[4];
#pragma unroll
    for (int kk = 0; kk < 4; ++kk) {
        union { s16x8 v; unsigned short u[8]; } Ah, Al;
#pragma unroll
        for (int j = 0; j < 8; ++j) {
            const int k = 32*kk + 8*lg + j;
            splitbf(W[k*HID + GA] * KSCALE, Ah.u[j], Al.u[j]);
        }
        ahi[kk] = Ah.v; alo[kk] = Al.v;
    }
    f32x4 cb;
    {
        const float4 bv = *(const float4*)(bias + Gc);
        cb[0] = bv.x*KSCALE; cb[1] = bv.y*KSCALE;
        cb[2] = bv.z*KSCALE; cb[3] = bv.w*KSCALE;
    }
    const int b = g*16 + lc;
    const float* xp = X + ((size_t)b*TLEN + t0)*HID + 8*lg;
    float* pp; size_t ST;
    if (wsOK) { pp = preB + ((size_t)g*TLEN + t0)*2048 + w*256 + l*4; ST = 2048; }
    else      { pp = preB + ((size_t)b*TLEN + t0)*HID + Gc;           ST = HID;  }

    for (int tt = 0; tt < 16; ++tt) {
        f32x4 c1 = cb;
        f32x4 c2 = {0.f,0.f,0.f,0.f};
        f32x4 c3 = {0.f,0.f,0.f,0.f};
#pragma unroll
        for (int kk = 0; kk < 4; ++kk) {
            const float4 f0 = *(const float4*)(xp + 32*kk);
            const float4 f1 = *(const float4*)(xp + 32*kk + 4);
            const uint32_t p01 = cvtpk(f0.x, f0.y), p23 = cvtpk(f0.z, f0.w);
            const uint32_t p45 = cvtpk(f1.x, f1.y), p67 = cvtpk(f1.z, f1.w);
            const float r0 = f0.x - asf(p01 << 16), r1 = f0.y - asf(p01 & 0xFFFF0000u);
            const float r2 = f0.z - asf(p23 << 16), r3 = f0.w - asf(p23 & 0xFFFF0000u);
            const float r4 = f1.x - asf(p45 << 16), r5 = f1.y - asf(p45 & 0xFFFF0000u);
            const float r6 = f1.z - asf(p67 << 16), r7 = f1.w - asf(p67 & 0xFFFF0000u);
            union { s16x8 v; uint32_t u[4]; } BH, BL;
            BH.u[0] = p01; BH.u[1] = p23; BH.u[2] = p45; BH.u[3] = p67;
            BL.u[0] = cvtpk(r0, r1); BL.u[1] = cvtpk(r2, r3);
            BL.u[2] = cvtpk(r4, r5); BL.u[3] = cvtpk(r6, r7);
            c1 = __builtin_amdgcn_mfma_f32_16x16x32_bf16(ahi[kk], BH.v, c1, 0, 0, 0);
            c2 = __builtin_amdgcn_mfma_f32_16x16x32_bf16(ahi[kk], BL.v, c2, 0, 0, 0);
            c3 = __builtin_amdgcn_mfma_f32_16x16x32_bf16(alo[kk], BH.v, c3, 0, 0, 0);
        }
        f32x4 c;
        c[0] = c1[0]+c2[0]+c3[0]; c[1] = c1[1]+c2[1]+c3[1];
        c[2] = c1[2]+c2[2]+c3[2]; c[3] = c1[3]+c2[3]+c3[3];
        *(f32x4*)pp = c;
        pp += ST;
        xp += HID;
    }
}

// ---------------- Phase 2: recurrence. 2 WGs x 512 threads; waves 0-3 handle
// batch-group 2*bid, waves 4-7 handle 2*bid+1 (independent chains -> 2 waves/
// SIMD of latency hiding). Within a group, wave wv owns K-chunk wv: own chunk's
// B operands stay in registers; cross-wave exchange is lane-aligned uint4s in a
// conflict-free XOR-swizzled LDS region. lgkm-only barrier keeps global
// prefetches in flight.
template<int WS>
__global__ __launch_bounds__(512) void rnn_rec(
        const float* preB, const float* __restrict__ W, float* out) {
    const int tid = threadIdx.x;
    const int l   = tid & 63;
    const int lg  = l >> 4;
    const int lc  = l & 15;
    const int w8  = tid >> 6;                                   // 0..7
    const int gg  = w8 >> 2;                                    // group within WG
    const int wvu = __builtin_amdgcn_readfirstlane(w8 & 3);     // chunk owner
    const int g   = blockIdx.x * 2 + gg;                        // global group

    __shared__ uint4 ldsb[2048];   // 32 KiB: 2 parity x 2 groups x 4 chunks x (hi,lo)
    {
        uint32_t* z = (uint32_t*)ldsb;
#pragma unroll
        for (int p = 0; p < 16; ++p) z[tid + 512*p] = 0u;   // h(-1) packs = 0
    }
    char* hb = (char*)ldsb + gg*8192;

    // A = W_h^T (scaled) split hi/lo, permuted rows
    s16x8 ahi[2][4], alo[2][4];
#pragma unroll
    for (int d = 0; d < 2; ++d) {
        const int GAd = 32*wvu + 4*d + 8*(lc>>2) + (lc&3);
#pragma unroll
        for (int kk = 0; kk < 4; ++kk) {
            union { s16x8 v; unsigned short u[8]; } Ah, Al;
#pragma unroll
            for (int j = 0; j < 8; ++j) {
                const int k = 32*kk + 8*lg + j;
                splitbf(W[(size_t)(HID + k)*HID + GAd] * KSCALE, Ah.u[j], Al.u[j]);
            }
            ahi[d][kk] = Ah.v; alo[d][kk] = Al.v;
        }
    }

    // conflict-free lane slot: 8 rows x 8 slots of 16B, slot rotated per row
    const int swz = ((l >> 3) << 7) + ((((l & 7) ^ ((l >> 3) & 7))) << 4);

    // pre pointers (phase-1 layout matches C tiles lane-for-lane)
    const float* pb; int PST, od;
    if (WS) { pb = preB + (size_t)g*TLEN*2048 + wvu*512 + l*4;            PST = 2048; od = 256; }
    else    { pb = preB + ((size_t)(g*16+lc)*TLEN)*HID + 32*wvu + 8*lg;   PST = HID;  od = 4;   }

    float* po  = out + ((size_t)(g*16+lc)*TLEN)*HID + 32*wvu + 8*lg;
    float* po2 = out + (size_t)64*TLEN*HID + 32*wvu + 8*lg;   // out[-1:] = batch 63
    const bool lastb = (g == NG-1) && (lc == 15);

    f32x4 pf[4][2];
#pragma unroll
    for (int u = 0; u < 4; ++u) {
        pf[u][0] = *(const f32x4*)(pb + (size_t)u*PST);
        pf[u][1] = *(const f32x4*)(pb + (size_t)u*PST + od);
    }

    s16x8 bh_own = {0,0,0,0,0,0,0,0};
    s16x8 bl_own = {0,0,0,0,0,0,0,0};

    __syncthreads();   // zero-init visible

    for (int tb = 0; tb < TLEN; tb += 4) {
#pragma unroll
        for (int u = 0; u < 4; ++u) {
            const int t   = tb + u;
            const int par = u & 1;                    // tb is even
            const char* rb = hb + (par ^ 1) * 16384;  // packs(t-1)
            char*       wb = hb + par * 16384;        // packs(t)

            // B fragments: 6 partner ds_read_b128 + own regs passthrough
#define LDCH(K, BH_, BL_) \
            s16x8 BH_, BL_; \
            if (K != wvu) { \
                BH_ = *(const s16x8*)(rb + (K)*2048 + swz); \
                BL_ = *(const s16x8*)(rb + (K)*2048 + 1024 + swz); \
            } else { BH_ = bh_own; BL_ = bl_own; }
            LDCH(0, bh0, bl0)
            LDCH(1, bh1, bl1)
            LDCH(2, bh2, bl2)
            LDCH(3, bh3, bl3)
#undef LDCH

            f32x4 c1[2], c2[2], c3[2];
            c1[0] = pf[u][0]; c1[1] = pf[u][1];
            c2[0] = f32x4{0.f,0.f,0.f,0.f}; c2[1] = f32x4{0.f,0.f,0.f,0.f};
            c3[0] = f32x4{0.f,0.f,0.f,0.f}; c3[1] = f32x4{0.f,0.f,0.f,0.f};

            // prefetch pre(t+4) while MFMAs run (pf[u] already consumed)
            if (t + 4 < TLEN) {
                pf[u][0] = *(const f32x4*)(pb + (size_t)(t+4)*PST);
                pf[u][1] = *(const f32x4*)(pb + (size_t)(t+4)*PST + od);
            }

#define MSTEP(K, BH_, BL_) \
            c1[0] = __builtin_amdgcn_mfma_f32_16x16x32_bf16(ahi[0][K], BH_, c1[0], 0,0,0); \
            c1[1] = __builtin_amdgcn_mfma_f32_16x16x32_bf16(ahi[1][K], BH_, c1[1], 0,0,0); \
            c2[0] = __builtin_amdgcn_mfma_f32_16x16x32_bf16(ahi[0][K], BL_, c2[0], 0,0,0); \
            c2[1] = __builtin_amdgcn_mfma_f32_16x16x32_bf16(ahi[1][K], BL_, c2[1], 0,0,0); \
            c3[0] = __builtin_amdgcn_mfma_f32_16x16x32_bf16(alo[0][K], BH_, c3[0], 0,0,0); \
            c3[1] = __builtin_amdgcn_mfma_f32_16x16x32_bf16(alo[1][K], BH_, c3[1], 0,0,0);
            MSTEP(0, bh0, bl0)
            MSTEP(1, bh1, bl1)
            MSTEP(2, bh2, bl2)
            MSTEP(3, bh3, bl3)
#undef MSTEP

            // h = tanh(s / (2log2e)) = 1 - 2/(exp2(s)+1)   (scale pre-folded)
            float hh[2][4];
#pragma unroll
            for (int d = 0; d < 2; ++d)
#pragma unroll
                for (int j = 0; j < 4; ++j) {
                    const float s = c1[d][j] + c2[d][j] + c3[d][j];
                    hh[d][j] = 1.f - 2.f * __builtin_amdgcn_rcpf(1.f + __builtin_amdgcn_exp2f(s));
                }

            // store: tile d covers hidden 32*wvu + 4*d + 8*lg + {0..3}
            float4 hv0, hv1;
            hv0.x = hh[0][0]; hv0.y = hh[0][1]; hv0.z = hh[0][2]; hv0.w = hh[0][3];
            hv1.x = hh[1][0]; hv1.y = hh[1][1]; hv1.z = hh[1][2]; hv1.w = hh[1][3];
            *(float4*)(po + (size_t)t*HID)     = hv0;
            *(float4*)(po + (size_t)t*HID + 4) = hv1;
            if (lastb) {
                *(float4*)(po2 + (size_t)t*HID)     = hv0;
                *(float4*)(po2 + (size_t)t*HID + 4) = hv1;
            }

            // pack h -> bf16 hi/lo; C layout == B layout for own chunk
            union { s16x8 v; uint4 q4; uint32_t q[4]; } BH, BL;
#pragma unroll
            for (int d = 0; d < 2; ++d) {
                const uint32_t xa = cvtpk(hh[d][0], hh[d][1]);
                const uint32_t xb = cvtpk(hh[d][2], hh[d][3]);
                const float r0 = hh[d][0] - asf(xa << 16);
                const float r1 = hh[d][1] - asf(xa & 0xFFFF0000u);
                const float r2 = hh[d][2] - asf(xb << 16);
                const float r3 = hh[d][3] - asf(xb & 0xFFFF0000u);
                BH.q[2*d]   = xa;            BH.q[2*d+1] = xb;
                BL.q[2*d]   = cvtpk(r0, r1); BL.q[2*d+1] = cvtpk(r2, r3);
            }
            bh_own = BH.v; bl_own = BL.v;
            *(uint4*)(wb + wvu*2048 + swz)        = BH.q4;
            *(uint4*)(wb + wvu*2048 + 1024 + swz) = BL.q4;

            if (WS) {
                // LDS-only drain + barrier: keeps global prefetch in flight
                asm volatile("s_waitcnt lgkmcnt(0)" ::: "memory");
                __builtin_amdgcn_s_barrier();
            } else {
                __syncthreads();   // fb path aliases pre into out: need full drain
            }
        }
    }
}

extern "C" void kernel_launch(void* const* d_in, const int* in_sizes, int n_in,
                              void* d_out, int out_size, void* d_ws, size_t ws_size,
                              hipStream_t stream) {
    const float* X    = (const float*)d_in[0];
    const float* Wt   = (const float*)d_in[1];
    const float* bias = (const float*)d_in[2];
    float* out = (float*)d_out;

    const size_t need = (size_t)NG * TLEN * 2048 * sizeof(float);   // 128 MB
    if (ws_size >= need) {
        float* preB = (float*)d_ws;
        pre_gemm<<<dim3(NG * 256), dim3(512), 0, stream>>>(X, Wt, bias, preB, 1);
        rnn_rec<1><<<dim3(2), dim3(512), 0, stream>>>(preB, Wt, out);
    } else {
        // pre stored inside d_out rows; overwritten at step t, read at t-4 —
        // ordered by the per-step full __syncthreads in rnn_rec<0>.
        pre_gemm<<<dim3(NG * 256), dim3(512), 0, stream>>>(X, Wt, bias, out, 0);
        rnn_rec<0><<<dim3(2), dim3(512), 0, stream>>>(out, Wt, out);
    }
}

// Round 3
// 3256.084 us; speedup vs baseline: 1.6218x; 1.6218x over previous
//
#include <hip/hip_runtime.h>
#include <stdint.h>

typedef float f32x4 __attribute__((ext_vector_type(4)));
typedef short s16x8 __attribute__((ext_vector_type(8)));

#define TLEN 4096
#define HID  128
#define NG   4   // 4 batch-groups of 16 (B = 64)
#define KSCALE 2.8853900817779268f   // 2*log2(e), folded into W_x, W_h, bias

static __device__ __forceinline__ float asf(uint32_t u) {
    union { uint32_t u; float f; } v; v.u = u; return v.f;
}
static __device__ __forceinline__ uint32_t cvtpk(float lo, float hi) {
    uint32_t r;
    asm("v_cvt_pk_bf16_f32 %0, %1, %2" : "=v"(r) : "v"(lo), "v"(hi));
    return r;
}
static __device__ __forceinline__ void splitbf(float v, unsigned short& hi, unsigned short& lo) {
    uint32_t p = cvtpk(v, 0.f);
    hi = (unsigned short)(p & 0xFFFFu);
    float r = v - asf((uint32_t)hi << 16);
    uint32_t q = cvtpk(r, 0.f);
    lo = (unsigned short)(q & 0xFFFFu);
}

// Row permutation: logical tile row r of wave w=(wv=w>>1, d=w&1) -> hidden idx
//   G = 32*wv + 4*d + 8*(r>>2) + (r&3)
// MFMA C-layout (col=lane&15, row=(lane>>4)*4+j) packed via cvt_pk is then
// exactly B-fragment content: chunk kk=wv, u32 q∈{2d,2d+1} holds rows
// 32kk+8lg+{2q,2q+1} (lo16=even, hi16=odd).
//
// LDS exchange layout (per parity, 8 KiB): chunk kk block @ kk*2048 =
//   [Hi d0: 512 | Hi d1: 512 | Lo d0: 512 | Lo d1: 512]
// Writer (wv,d): two ds_write_b64 at lane*8 into its 512-B sub-blocks
// (contiguous -> minimum bank cycles). Reader: four ds_read_b64 per chunk
// (contiguous sub-blocks) assemble the s16x8 fragments. Conflict-free.

// ---------------- Phase 1: pre = (X @ W_x + bias) * 2log2e, permuted layout
__global__ __launch_bounds__(512) void pre_gemm(
        const float* __restrict__ X, const float* __restrict__ W,
        const float* __restrict__ bias, float* preB, int wsOK) {
    const int tid = threadIdx.x;
    const int w  = tid >> 6;      // 0..7 -> (wv = w>>1, d = w&1)
    const int l  = tid & 63;
    const int lg = l >> 4;
    const int lc = l & 15;
    const int g  = blockIdx.x & (NG - 1);
    const int t0 = (blockIdx.x >> 2) << 4;   // 16 timesteps per WG

    const int wv = w >> 1, dd = w & 1;
    const int GA = 32*wv + 4*dd + 8*(lc>>2) + (lc&3);  // A-row (lane lc) global col
    const int Gc = 32*wv + 4*dd + 8*lg;                // C-row base (this lane)

    // A = W_x^T (scaled) split hi/lo: A[r=lc][k], k = 32kk+8lg+j
    s16x8 ahi[4], alo[4];
#pragma unroll
    for (int kk = 0; kk < 4; ++kk) {
        union { s16x8 v; unsigned short u[8]; } Ah, Al;
#pragma unroll
        for (int j = 0; j < 8; ++j) {
            const int k = 32*kk + 8*lg + j;
            splitbf(W[k*HID + GA] * KSCALE, Ah.u[j], Al.u[j]);
        }
        ahi[kk] = Ah.v; alo[kk] = Al.v;
    }
    f32x4 cb;
    {
        const float4 bv = *(const float4*)(bias + Gc);
        cb[0] = bv.x*KSCALE; cb[1] = bv.y*KSCALE;
        cb[2] = bv.z*KSCALE; cb[3] = bv.w*KSCALE;
    }
    const int b = g*16 + lc;
    const float* xp = X + ((size_t)b*TLEN + t0)*HID + 8*lg;
    float* pp; size_t ST;
    if (wsOK) { pp = preB + ((size_t)g*TLEN + t0)*2048 + w*256 + l*4; ST = 2048; }
    else      { pp = preB + ((size_t)b*TLEN + t0)*HID + Gc;           ST = HID;  }

    for (int tt = 0; tt < 16; ++tt) {
        f32x4 c1 = cb;
        f32x4 c2 = {0.f,0.f,0.f,0.f};
        f32x4 c3 = {0.f,0.f,0.f,0.f};
#pragma unroll
        for (int kk = 0; kk < 4; ++kk) {
            const float4 f0 = *(const float4*)(xp + 32*kk);
            const float4 f1 = *(const float4*)(xp + 32*kk + 4);
            const uint32_t p01 = cvtpk(f0.x, f0.y), p23 = cvtpk(f0.z, f0.w);
            const uint32_t p45 = cvtpk(f1.x, f1.y), p67 = cvtpk(f1.z, f1.w);
            const float r0 = f0.x - asf(p01 << 16), r1 = f0.y - asf(p01 & 0xFFFF0000u);
            const float r2 = f0.z - asf(p23 << 16), r3 = f0.w - asf(p23 & 0xFFFF0000u);
            const float r4 = f1.x - asf(p45 << 16), r5 = f1.y - asf(p45 & 0xFFFF0000u);
            const float r6 = f1.z - asf(p67 << 16), r7 = f1.w - asf(p67 & 0xFFFF0000u);
            union { s16x8 v; uint32_t u[4]; } BH, BL;
            BH.u[0] = p01; BH.u[1] = p23; BH.u[2] = p45; BH.u[3] = p67;
            BL.u[0] = cvtpk(r0, r1); BL.u[1] = cvtpk(r2, r3);
            BL.u[2] = cvtpk(r4, r5); BL.u[3] = cvtpk(r6, r7);
            c1 = __builtin_amdgcn_mfma_f32_16x16x32_bf16(ahi[kk], BH.v, c1, 0, 0, 0);
            c2 = __builtin_amdgcn_mfma_f32_16x16x32_bf16(ahi[kk], BL.v, c2, 0, 0, 0);
            c3 = __builtin_amdgcn_mfma_f32_16x16x32_bf16(alo[kk], BH.v, c3, 0, 0, 0);
        }
        f32x4 c;
        c[0] = c1[0]+c2[0]+c3[0]; c[1] = c1[1]+c2[1]+c3[1];
        c[2] = c1[2]+c2[2]+c3[2]; c[3] = c1[3]+c2[3]+c3[3];
        *(f32x4*)pp = c;
        pp += ST;
        xp += HID;
    }
}

// ---------------- Phase 2: recurrence. 8 waves per group (2/SIMD), 1 group/WG,
// 4 WGs. Wave w owns ONE 16-row permuted tile: 12 MFMAs + 4 tanh + 1 write pair
// per step (shortest per-wave serial chain). Exchange through the SoA LDS
// layout above: all reads/writes are contiguous 512-B blocks (zero conflicts).
// lgkm-only barrier keeps global pre-prefetch in flight.
template<int WS>
__global__ __launch_bounds__(512) void rnn_rec(
        const float* preB, const float* __restrict__ W, float* out) {
    const int tid = threadIdx.x;
    const int l   = tid & 63;
    const int lg  = l >> 4;
    const int lc  = l & 15;
    const int w8  = tid >> 6;                                   // 0..7
    const int wv  = __builtin_amdgcn_readfirstlane(w8 >> 1);    // chunk
    const int d   = __builtin_amdgcn_readfirstlane(w8 & 1);     // half
    const int g   = blockIdx.x;

    __shared__ uint4 ldsb[1024];   // 16 KiB: 2 parity x 4 chunks x (hi,lo) x 2 halves
    char* hb = (char*)ldsb;
    {
        uint32_t* z = (uint32_t*)ldsb;
#pragma unroll
        for (int p = 0; p < 8; ++p) z[tid + 512*p] = 0u;   // h(-1) packs = 0
    }

    // A = W_h^T (scaled) split hi/lo, permuted rows for this wave's tile
    s16x8 ahi[4], alo[4];
    const int GA = 32*wv + 4*d + 8*(lc>>2) + (lc&3);
#pragma unroll
    for (int kk = 0; kk < 4; ++kk) {
        union { s16x8 v; unsigned short u[8]; } Ah, Al;
#pragma unroll
        for (int j = 0; j < 8; ++j) {
            const int k = 32*kk + 8*lg + j;
            splitbf(W[(size_t)(HID + k)*HID + GA] * KSCALE, Ah.u[j], Al.u[j]);
        }
        ahi[kk] = Ah.v; alo[kk] = Al.v;
    }

    const int Gc = 32*wv + 4*d + 8*lg;          // this lane's 4 output rows
    const int rbase = 8*l;                      // byte offset in 512-B sub-block
    const int wbyte = wv*2048 + d*512 + rbase;  // hi write slot (lo at +1024)

    // pre pointer (phase-1 layout matches this wave's C tile lane-for-lane)
    const float* pb; int PST;
    if (WS) { pb = preB + (size_t)g*TLEN*2048 + w8*256 + l*4;          PST = 2048; }
    else    { pb = preB + ((size_t)(g*16+lc)*TLEN)*HID + Gc;           PST = HID;  }

    float* po  = out + ((size_t)(g*16+lc)*TLEN)*HID + Gc;
    float* po2 = out + (size_t)64*TLEN*HID + Gc;   // out[-1:] = batch 63
    const bool lastb = (g == NG-1) && (lc == 15);

    f32x4 pf[4];
#pragma unroll
    for (int u = 0; u < 4; ++u) pf[u] = *(const f32x4*)(pb + (size_t)u*PST);

    __syncthreads();   // zero-init visible

    for (int tb = 0; tb < TLEN; tb += 4) {
#pragma unroll
        for (int u = 0; u < 4; ++u) {
            const int t = tb + u;
            const char* rb = hb + ((u & 1) ^ 1) * 8192;   // packs(t-1)
            char*       wb = hb + (u & 1) * 8192;         // packs(t)

            // B fragments: 16 contiguous ds_read_b64 (fusable to read2_b64)
            union F { s16x8 v; uint2 p[2]; };
            F BH[4], BL[4];
#pragma unroll
            for (int kk = 0; kk < 4; ++kk) {
                const char* cb = rb + kk*2048 + rbase;
                BH[kk].p[0] = *(const uint2*)(cb);
                BH[kk].p[1] = *(const uint2*)(cb + 512);
                BL[kk].p[0] = *(const uint2*)(cb + 1024);
                BL[kk].p[1] = *(const uint2*)(cb + 1536);
            }

            f32x4 c1 = pf[u];
            f32x4 c2 = {0.f,0.f,0.f,0.f};
            f32x4 c3 = {0.f,0.f,0.f,0.f};

            // prefetch pre(t+4) while MFMAs run (pf[u] already consumed)
            if (t + 4 < TLEN) pf[u] = *(const f32x4*)(pb + (size_t)(t+4)*PST);

#pragma unroll
            for (int kk = 0; kk < 4; ++kk) {
                c1 = __builtin_amdgcn_mfma_f32_16x16x32_bf16(ahi[kk], BH[kk].v, c1, 0,0,0);
                c2 = __builtin_amdgcn_mfma_f32_16x16x32_bf16(ahi[kk], BL[kk].v, c2, 0,0,0);
                c3 = __builtin_amdgcn_mfma_f32_16x16x32_bf16(alo[kk], BH[kk].v, c3, 0,0,0);
            }

            // h = tanh(s / (2log2e)) = 1 - 2/(exp2(s)+1)   (scale pre-folded)
            const float h0 = 1.f - 2.f * __builtin_amdgcn_rcpf(1.f + __builtin_amdgcn_exp2f(c1[0]+c2[0]+c3[0]));
            const float h1 = 1.f - 2.f * __builtin_amdgcn_rcpf(1.f + __builtin_amdgcn_exp2f(c1[1]+c2[1]+c3[1]));
            const float h2 = 1.f - 2.f * __builtin_amdgcn_rcpf(1.f + __builtin_amdgcn_exp2f(c1[2]+c2[2]+c3[2]));
            const float h3 = 1.f - 2.f * __builtin_amdgcn_rcpf(1.f + __builtin_amdgcn_exp2f(c1[3]+c2[3]+c3[3]));

            float4 hv; hv.x = h0; hv.y = h1; hv.z = h2; hv.w = h3;
            *(float4*)(po + (size_t)t*HID) = hv;
            if (lastb) *(float4*)(po2 + (size_t)t*HID) = hv;

            // pack h -> bf16 hi/lo pair; C layout == B layout (own q-pair)
            const uint32_t xa = cvtpk(h0, h1), xb = cvtpk(h2, h3);
            const float l0 = h0 - asf(xa << 16), l1 = h1 - asf(xa & 0xFFFF0000u);
            const float l2 = h2 - asf(xb << 16), l3 = h3 - asf(xb & 0xFFFF0000u);
            uint2 wh; wh.x = xa; wh.y = xb;
            uint2 wl; wl.x = cvtpk(l0, l1); wl.y = cvtpk(l2, l3);
            *(uint2*)(wb + wbyte)        = wh;
            *(uint2*)(wb + 1024 + wbyte) = wl;

            if (WS) {
                // LDS-only drain + barrier: keeps global prefetch in flight
                asm volatile("s_waitcnt lgkmcnt(0)" ::: "memory");
                __builtin_amdgcn_s_barrier();
            } else {
                __syncthreads();   // fb path aliases pre into out: full drain
            }
        }
    }
}

extern "C" void kernel_launch(void* const* d_in, const int* in_sizes, int n_in,
                              void* d_out, int out_size, void* d_ws, size_t ws_size,
                              hipStream_t stream) {
    const float* X    = (const float*)d_in[0];
    const float* Wt   = (const float*)d_in[1];
    const float* bias = (const float*)d_in[2];
    float* out = (float*)d_out;

    const size_t need = (size_t)NG * TLEN * 2048 * sizeof(float);   // 128 MB
    if (ws_size >= need) {
        float* preB = (float*)d_ws;
        pre_gemm<<<dim3(NG * 256), dim3(512), 0, stream>>>(X, Wt, bias, preB, 1);
        rnn_rec<1><<<dim3(NG), dim3(512), 0, stream>>>(preB, Wt, out);
    } else {
        // pre stored inside d_out rows; overwritten at step t, read at t-4 —
        // each lane reads/writes only its own (batch,row) slice, ordered by
        // the per-step full __syncthreads in rnn_rec<0>.
        pre_gemm<<<dim3(NG * 256), dim3(512), 0, stream>>>(X, Wt, bias, out, 0);
        rnn_rec<0><<<dim3(NG), dim3(512), 0, stream>>>(out, Wt, out);
    }
}

// Round 4
// 2870.365 us; speedup vs baseline: 1.8397x; 1.1344x over previous
//
#include <hip/hip_runtime.h>
#include <stdint.h>

typedef float f32x4 __attribute__((ext_vector_type(4)));
typedef short s16x8 __attribute__((ext_vector_type(8)));

#define TLEN 4096
#define HID  128
#define PGRP 4   // pre_gemm batch grouping (16 batches each)
#define RGRP 8   // rnn_rec groups: 8 groups x 8 batches (cols replicated 2x)
#define KSCALE 2.8853900817779268f   // 2*log2(e), folded into W_x, W_h, bias

static __device__ __forceinline__ float asf(uint32_t u) {
    union { uint32_t u; float f; } v; v.u = u; return v.f;
}
static __device__ __forceinline__ uint32_t cvtpk(float lo, float hi) {
    uint32_t r;
    asm("v_cvt_pk_bf16_f32 %0, %1, %2" : "=v"(r) : "v"(lo), "v"(hi));
    return r;
}
static __device__ __forceinline__ void splitbf(float v, unsigned short& hi, unsigned short& lo) {
    uint32_t p = cvtpk(v, 0.f);
    hi = (unsigned short)(p & 0xFFFFu);
    float r = v - asf((uint32_t)hi << 16);
    uint32_t q = cvtpk(r, 0.f);
    lo = (unsigned short)(q & 0xFFFFu);
}

// Row permutation: logical tile row r of wave w=(wv=w>>1, d=w&1) -> hidden idx
//   G = 32*wv + 4*d + 8*(r>>2) + (r&3)
// MFMA C-layout (col=lane&15, row=(lane>>4)*4+j) packed via cvt_pk is then
// exactly B-fragment content: chunk kk=wv, u32 q∈{2d,2d+1} holds rows
// 32kk+8lg+{2q,2q+1}.
//
// rnn_rec LDS layout (per parity, 4 KiB): chunk kk HI block @ kk*512,
// LO block @ 2048+kk*512. Slot s = lg*8 + col (col=0..7, 8 real batches),
// 16 B per slot (u32 q=0..3 of the fragment). Reader lane (lg,lc) does one
// ds_read_b128 at slot (lg, lc&7): lanes lc and lc+8 share the address ->
// HW broadcast, 512 B unique per read (~half the data cycles of a full 1 KiB
// b128). Writer wave (wv,d), lanes lc<8 only: ds_write_b64 of {q2d,q2d+1}
// at slot(lg,lc)+8d.

// ---------------- Phase 1: pre = (X @ W_x + bias) * 2log2e, permuted layout
__global__ __launch_bounds__(512) void pre_gemm(
        const float* __restrict__ X, const float* __restrict__ W,
        const float* __restrict__ bias, float* preB, int wsOK) {
    const int tid = threadIdx.x;
    const int w  = tid >> 6;      // 0..7 -> (wv = w>>1, d = w&1)
    const int l  = tid & 63;
    const int lg = l >> 4;
    const int lc = l & 15;
    const int go = blockIdx.x & (PGRP - 1);
    const int t0 = (blockIdx.x >> 2) << 4;   // 16 timesteps per WG

    const int wv = w >> 1, dd = w & 1;
    const int GA = 32*wv + 4*dd + 8*(lc>>2) + (lc&3);  // A-row (lane lc) global col
    const int Gc = 32*wv + 4*dd + 8*lg;                // C-row base (this lane)

    // A = W_x^T (scaled) split hi/lo: A[r=lc][k], k = 32kk+8lg+j
    s16x8 ahi[4], alo[4];
#pragma unroll
    for (int kk = 0; kk < 4; ++kk) {
        union { s16x8 v; unsigned short u[8]; } Ah, Al;
#pragma unroll
        for (int j = 0; j < 8; ++j) {
            const int k = 32*kk + 8*lg + j;
            splitbf(W[k*HID + GA] * KSCALE, Ah.u[j], Al.u[j]);
        }
        ahi[kk] = Ah.v; alo[kk] = Al.v;
    }
    f32x4 cb;
    {
        const float4 bv = *(const float4*)(bias + Gc);
        cb[0] = bv.x*KSCALE; cb[1] = bv.y*KSCALE;
        cb[2] = bv.z*KSCALE; cb[3] = bv.w*KSCALE;
    }
    const int b = go*16 + lc;
    const float* xp = X + ((size_t)b*TLEN + t0)*HID + 8*lg;
    float* pp; size_t ST;
    if (wsOK) {
        // rec-group gn = b>>3; per-(g,t) block of 1024 f32: slot w*128 + col*16 + lg*4
        const int gn = go*2 + (lc >> 3);
        pp = preB + ((size_t)gn*TLEN + t0)*1024 + w*128 + (lc&7)*16 + lg*4;
        ST = 1024;
    } else {
        pp = preB + ((size_t)b*TLEN + t0)*HID + Gc;
        ST = HID;
    }

    for (int tt = 0; tt < 16; ++tt) {
        f32x4 c1 = cb;
        f32x4 c2 = {0.f,0.f,0.f,0.f};
        f32x4 c3 = {0.f,0.f,0.f,0.f};
#pragma unroll
        for (int kk = 0; kk < 4; ++kk) {
            const float4 f0 = *(const float4*)(xp + 32*kk);
            const float4 f1 = *(const float4*)(xp + 32*kk + 4);
            const uint32_t p01 = cvtpk(f0.x, f0.y), p23 = cvtpk(f0.z, f0.w);
            const uint32_t p45 = cvtpk(f1.x, f1.y), p67 = cvtpk(f1.z, f1.w);
            const float r0 = f0.x - asf(p01 << 16), r1 = f0.y - asf(p01 & 0xFFFF0000u);
            const float r2 = f0.z - asf(p23 << 16), r3 = f0.w - asf(p23 & 0xFFFF0000u);
            const float r4 = f1.x - asf(p45 << 16), r5 = f1.y - asf(p45 & 0xFFFF0000u);
            const float r6 = f1.z - asf(p67 << 16), r7 = f1.w - asf(p67 & 0xFFFF0000u);
            union { s16x8 v; uint32_t u[4]; } BH, BL;
            BH.u[0] = p01; BH.u[1] = p23; BH.u[2] = p45; BH.u[3] = p67;
            BL.u[0] = cvtpk(r0, r1); BL.u[1] = cvtpk(r2, r3);
            BL.u[2] = cvtpk(r4, r5); BL.u[3] = cvtpk(r6, r7);
            c1 = __builtin_amdgcn_mfma_f32_16x16x32_bf16(ahi[kk], BH.v, c1, 0, 0, 0);
            c2 = __builtin_amdgcn_mfma_f32_16x16x32_bf16(ahi[kk], BL.v, c2, 0, 0, 0);
            c3 = __builtin_amdgcn_mfma_f32_16x16x32_bf16(alo[kk], BH.v, c3, 0, 0, 0);
        }
        f32x4 c;
        c[0] = c1[0]+c2[0]+c3[0]; c[1] = c1[1]+c2[1]+c3[1];
        c[2] = c1[2]+c2[2]+c3[2]; c[3] = c1[3]+c2[3]+c3[3];
        *(f32x4*)pp = c;
        pp += ST;
        xp += HID;
    }
}

// ---------------- Phase 2: recurrence. 8 WGs (1 group of 8 batches each),
// 8 waves/WG (2/SIMD). MFMA B-columns 8..15 are replicas of 0..7: replica
// lanes read the SAME LDS slots (HW broadcast -> half the LDS data cycles),
// compute identical h, and are masked off for LDS/global writes.
template<int WS>
__global__ __launch_bounds__(512) void rnn_rec(
        const float* preB, const float* __restrict__ W, float* out) {
    const int tid = threadIdx.x;
    const int l   = tid & 63;
    const int lg  = l >> 4;
    const int lc  = l & 15;
    const int w8  = tid >> 6;                                   // 0..7
    const int wv  = __builtin_amdgcn_readfirstlane(w8 >> 1);    // chunk
    const int d   = __builtin_amdgcn_readfirstlane(w8 & 1);     // half
    const int g   = blockIdx.x;                                 // 0..7

    __shared__ uint4 ldsb[512];   // 8 KiB: 2 parity x (HI 2K | LO 2K)
    char* hb = (char*)ldsb;
    {
        uint32_t* z = (uint32_t*)ldsb;
#pragma unroll
        for (int p = 0; p < 4; ++p) z[tid + 512*p] = 0u;   // h(-1) packs = 0
    }

    // A = W_h^T (scaled) split hi/lo, permuted rows for this wave's tile
    s16x8 ahi[4], alo[4];
    const int GA = 32*wv + 4*d + 8*(lc>>2) + (lc&3);
#pragma unroll
    for (int kk = 0; kk < 4; ++kk) {
        union { s16x8 v; unsigned short u[8]; } Ah, Al;
#pragma unroll
        for (int j = 0; j < 8; ++j) {
            const int k = 32*kk + 8*lg + j;
            splitbf(W[(size_t)(HID + k)*HID + GA] * KSCALE, Ah.u[j], Al.u[j]);
        }
        ahi[kk] = Ah.v; alo[kk] = Al.v;
    }

    const int Gc = 32*wv + 4*d + 8*lg;               // this lane's 4 output rows
    const int slotR = 16*(lg*8 + (lc&7));            // read slot (broadcast pairs)
    const int slotW = 16*(lg*8 + lc) + 8*d;          // write slot (lc<8 only)
    const bool prim = (lc < 8);

    // pre pointer (phase-1 layout matches this wave's C tile lane-for-lane)
    const float* pb; int PST;
    if (WS) { pb = preB + (size_t)g*TLEN*1024 + w8*128 + (lc&7)*16 + lg*4;  PST = 1024; }
    else    { pb = preB + ((size_t)(g*8 + (lc&7))*TLEN)*HID + Gc;           PST = HID;  }

    float* po  = out + ((size_t)(g*8 + (lc&7))*TLEN)*HID + Gc;
    float* po2 = out + (size_t)64*TLEN*HID + Gc;   // out[-1:] = batch 63
    const bool lastb = (g == RGRP-1) && (lc == 7);

    f32x4 pf[4];
#pragma unroll
    for (int u = 0; u < 4; ++u) pf[u] = *(const f32x4*)(pb + (size_t)u*PST);

    __syncthreads();   // zero-init visible

    for (int tb = 0; tb < TLEN; tb += 4) {
#pragma unroll
        for (int u = 0; u < 4; ++u) {
            const int t = tb + u;
            const char* rb = hb + ((u & 1) ^ 1) * 4096;   // packs(t-1)
            char*       wb = hb + (u & 1) * 4096;         // packs(t)

            // B fragments: 8 ds_read_b128, each 512 B unique (broadcast pairs)
            union F { s16x8 v; };
            F BH[4], BL[4];
#pragma unroll
            for (int kk = 0; kk < 4; ++kk) {
                BH[kk].v = *(const s16x8*)(rb + kk*512 + slotR);
                BL[kk].v = *(const s16x8*)(rb + 2048 + kk*512 + slotR);
            }

            f32x4 c1 = pf[u];
            f32x4 c2 = {0.f,0.f,0.f,0.f};
            f32x4 c3 = {0.f,0.f,0.f,0.f};

            // prefetch pre(t+4) while MFMAs run (pf[u] already consumed)
            if (t + 4 < TLEN) pf[u] = *(const f32x4*)(pb + (size_t)(t+4)*PST);

#pragma unroll
            for (int kk = 0; kk < 4; ++kk) {
                c1 = __builtin_amdgcn_mfma_f32_16x16x32_bf16(ahi[kk], BH[kk].v, c1, 0,0,0);
                c2 = __builtin_amdgcn_mfma_f32_16x16x32_bf16(ahi[kk], BL[kk].v, c2, 0,0,0);
                c3 = __builtin_amdgcn_mfma_f32_16x16x32_bf16(alo[kk], BH[kk].v, c3, 0,0,0);
            }

            // h = tanh(s / (2log2e)) = 1 - 2/(exp2(s)+1)   (scale pre-folded)
            const float h0 = 1.f - 2.f * __builtin_amdgcn_rcpf(1.f + __builtin_amdgcn_exp2f(c1[0]+c2[0]+c3[0]));
            const float h1 = 1.f - 2.f * __builtin_amdgcn_rcpf(1.f + __builtin_amdgcn_exp2f(c1[1]+c2[1]+c3[1]));
            const float h2 = 1.f - 2.f * __builtin_amdgcn_rcpf(1.f + __builtin_amdgcn_exp2f(c1[2]+c2[2]+c3[2]));
            const float h3 = 1.f - 2.f * __builtin_amdgcn_rcpf(1.f + __builtin_amdgcn_exp2f(c1[3]+c2[3]+c3[3]));

            // pack h -> bf16 hi/lo pair; C layout == B layout (own q-pair)
            const uint32_t xa = cvtpk(h0, h1), xb = cvtpk(h2, h3);
            const float l0 = h0 - asf(xa << 16), l1 = h1 - asf(xa & 0xFFFF0000u);
            const float l2 = h2 - asf(xb << 16), l3 = h3 - asf(xb & 0xFFFF0000u);
            uint2 wh; wh.x = xa; wh.y = xb;
            uint2 wl; wl.x = cvtpk(l0, l1); wl.y = cvtpk(l2, l3);
            if (prim) {
                *(uint2*)(wb + wv*512 + slotW)        = wh;
                *(uint2*)(wb + 2048 + wv*512 + slotW) = wl;
                float4 hv; hv.x = h0; hv.y = h1; hv.z = h2; hv.w = h3;
                *(float4*)(po + (size_t)t*HID) = hv;
                if (lastb) *(float4*)(po2 + (size_t)t*HID) = hv;
            }

            if (WS) {
                // LDS-only drain + barrier: keeps global prefetch in flight
                asm volatile("s_waitcnt lgkmcnt(0)" ::: "memory");
                __builtin_amdgcn_s_barrier();
            } else {
                __syncthreads();   // fb path aliases pre into out: full drain
            }
        }
    }
}

extern "C" void kernel_launch(void* const* d_in, const int* in_sizes, int n_in,
                              void* d_out, int out_size, void* d_ws, size_t ws_size,
                              hipStream_t stream) {
    const float* X    = (const float*)d_in[0];
    const float* Wt   = (const float*)d_in[1];
    const float* bias = (const float*)d_in[2];
    float* out = (float*)d_out;

    const size_t need = (size_t)RGRP * TLEN * 1024 * sizeof(float);   // 128 MB
    if (ws_size >= need) {
        float* preB = (float*)d_ws;
        pre_gemm<<<dim3(PGRP * 256), dim3(512), 0, stream>>>(X, Wt, bias, preB, 1);
        rnn_rec<1><<<dim3(RGRP), dim3(512), 0, stream>>>(preB, Wt, out);
    } else {
        // pre stored inside d_out rows; overwritten at step t, read at t-4 —
        // each lane reads/writes only its own (batch,row) slice, ordered by
        // the per-step full __syncthreads in rnn_rec<0>.
        pre_gemm<<<dim3(PGRP * 256), dim3(512), 0, stream>>>(X, Wt, bias, out, 0);
        rnn_rec<0><<<dim3(RGRP), dim3(512), 0, stream>>>(out, Wt, out);
    }
}